// Round 9
// baseline (272.308 us; speedup 1.0000x reference)
//
#include <hip/hip_runtime.h>
#include <hip/hip_bf16.h>
#include <hip/hip_fp16.h>

// GraphSAGE 2-layer forward. N=100000, E=1.6M, C: 32 -> 64 -> 32.
//
// Round-9: layer1 was VALU+LDS-instruction bound (fp16 gather halved FETCH,
// time flat, VALU 62%): the per-node dense phases issued ~224 scalar
// ds_read_b32 (per-k weight reads). Fix:
//  - dense split into its own kernel: fp16 pre-transposed weights held in
//    REGISTERS per lane (loaded once per wave, 4 nodes amortized), agg/x rows
//    as uniform 16B loads, v_dot2_f32_f16 inner product (fp32 accum).
//  - gather1 is gather-only (no weight LDS -> full occupancy).
// partition / scan / csr / layer2 unchanged from round 8.

#define BUCKET_SHIFT 8
#define BUCKET_SPAN  256
#define BUCKET_CAP   8192
#define PART_ITEMS   32
#define PART_TILE    (256 * PART_ITEMS)   // 8192 edges

typedef _Float16 f16x2 __attribute__((ext_vector_type(2)));

__device__ __forceinline__ float fdot2u(unsigned a, unsigned b, float c) {
#if __has_builtin(__builtin_amdgcn_fdot2)
    f16x2 av, bv;
    __builtin_memcpy(&av, &a, 4);
    __builtin_memcpy(&bv, &b, 4);
    return __builtin_amdgcn_fdot2(av, bv, c, false);
#else
    __half2 ah = *reinterpret_cast<__half2*>(&a);
    __half2 bh = *reinterpret_cast<__half2*>(&b);
    float2 fa = __half22float2(ah), fb = __half22float2(bh);
    return c + fa.x * fb.x + fa.y * fb.y;
#endif
}

// ---- one-time: weights -> fp16, transposed (output-channel-major) ----
// wT halves layout: [0:2048)   w1lT[oc][k]  = W1l[k*64+oc]   (64 x 32)
//                   [2048:4096) w1rT[oc][k] = W1r[k*64+oc]
//                   [4096:6144) w2lT[c][kk] = W2l[kk*32+c]   (32 x 64)
//                   [6144:8192) w2rT[c][kk] = W2r[kk*32+c]
__global__ __launch_bounds__(512) void wprep_kernel(
        const float* __restrict__ W1l, const float* __restrict__ W1r,
        const float* __restrict__ W2l, const float* __restrict__ W2r,
        __half* __restrict__ wT) {
    for (int i = threadIdx.x; i < 8192; i += 512) {
        int region = i >> 11;
        int off = i & 2047;
        float v;
        if (region == 0)      { int oc = off >> 5, k = off & 31; v = W1l[k * 64 + oc]; }
        else if (region == 1) { int oc = off >> 5, k = off & 31; v = W1r[k * 64 + oc]; }
        else if (region == 2) { int c = off >> 6, k = off & 63;  v = W2l[k * 32 + c]; }
        else                  { int c = off >> 6, k = off & 63;  v = W2r[k * 32 + c]; }
        wT[i] = __float2half_rn(v);
    }
}

// ---- cast x (fp32) -> xh (fp16), 8 elems/thread ----
__global__ __launch_bounds__(256) void cast_x_kernel(
        const float* __restrict__ x, __half* __restrict__ xh, int total8) {
    int i = blockIdx.x * blockDim.x + threadIdx.x;
    if (i < total8) {
        float4 a = ((const float4*)x)[(size_t)i * 2];
        float4 b = ((const float4*)x)[(size_t)i * 2 + 1];
        struct alignas(16) H8 { __half2 a, b, c, d; } o;
        o.a = __floats2half2_rn(a.x, a.y);
        o.b = __floats2half2_rn(a.z, a.w);
        o.c = __floats2half2_rn(b.x, b.y);
        o.d = __floats2half2_rn(b.z, b.w);
        ((H8*)xh)[i] = o;
    }
}

// ---- partition: scatter edges into bucket regions, packed ----
__global__ __launch_bounds__(256) void partition_kernel(
        const int* __restrict__ src, const int* __restrict__ dst,
        int* __restrict__ cursorB, int* __restrict__ edgesB, int E, int nbuck) {
    __shared__ int hist[512];
    __shared__ int rank_[512];
    __shared__ int base[512];
    const int tid = threadIdx.x;
    const int tbase = blockIdx.x * PART_TILE;

    for (int i = tid; i < 512; i += 256) { hist[i] = 0; rank_[i] = 0; }
    __syncthreads();

#pragma unroll
    for (int it = 0; it < PART_ITEMS; ++it) {
        int idx = tbase + it * 256 + tid;
        if (idx < E) atomicAdd(&hist[dst[idx] >> BUCKET_SHIFT], 1);
    }
    __syncthreads();

    for (int i = tid; i < nbuck; i += 256) {
        int h = hist[i];
        base[i] = h ? atomicAdd(&cursorB[i], h) : 0;
    }
    __syncthreads();

#pragma unroll
    for (int it = 0; it < PART_ITEMS; ++it) {
        int idx = tbase + it * 256 + tid;
        if (idx < E) {
            int d = dst[idx];
            int b = d >> BUCKET_SHIFT;
            int ld = d & (BUCKET_SPAN - 1);
            int r = atomicAdd(&rank_[b], 1);
            edgesB[(size_t)b * BUCKET_CAP + base[b] + r] = (ld << 24) | src[idx];
        }
    }
}

__global__ __launch_bounds__(512) void bucket_scan_kernel(
        const int* __restrict__ cursorB, int* __restrict__ bucketStart, int nbuck) {
    __shared__ int s[512];
    int t = threadIdx.x;
    int v = (t < nbuck) ? cursorB[t] : 0;
    s[t] = v;
    __syncthreads();
    for (int off = 1; off < 512; off <<= 1) {
        int a = (t >= off) ? s[t - off] : 0;
        __syncthreads();
        s[t] += a;
        __syncthreads();
    }
    if (t < nbuck) bucketStart[t] = s[t] - v;
}

__global__ __launch_bounds__(256) void bucket_csr_kernel(
        const int* __restrict__ cursorB, const int* __restrict__ bucketStart,
        const int* __restrict__ edgesB, int* __restrict__ row_start,
        int* __restrict__ sorted_src, int N, int nbuck) {
    __shared__ int cnt[BUCKET_SPAN];
    __shared__ int cur[BUCKET_SPAN];
    __shared__ int sc[BUCKET_SPAN];
    __shared__ int sorted[BUCKET_CAP];

    const int b = blockIdx.x;
    const int t = threadIdx.x;
    const int nodeBase = b << BUCKET_SHIFT;
    const int span = min(BUCKET_SPAN, N - nodeBase);
    const int size = cursorB[b];
    const int gstart = bucketStart[b];
    const int* eb = edgesB + (size_t)b * BUCKET_CAP;

    cnt[t] = 0;
    __syncthreads();
    for (int i = t; i < size; i += 256) atomicAdd(&cnt[((unsigned)eb[i]) >> 24], 1);
    __syncthreads();

    sc[t] = cnt[t];
    __syncthreads();
    for (int off = 1; off < BUCKET_SPAN; off <<= 1) {
        int a = (t >= off) ? sc[t - off] : 0;
        __syncthreads();
        sc[t] += a;
        __syncthreads();
    }
    int excl = sc[t] - cnt[t];
    if (t < span) row_start[nodeBase + t] = gstart + excl;
    if (b == nbuck - 1 && t == 0) row_start[N] = gstart + size;
    cur[t] = excl;
    __syncthreads();

    for (int i = t; i < size; i += 256) {
        int p = eb[i];
        int r = atomicAdd(&cur[((unsigned)p) >> 24], 1);
        sorted[r] = p & 0xFFFFFF;
    }
    __syncthreads();
    for (int i = t; i < size; i += 256) sorted_src[gstart + i] = sorted[i];
}

// ---- wave-cooperative gather-sum of fp16 rows (32ch = 8 float2 units) ----
__device__ __forceinline__ float4 gather_sum_f16(const float2* __restrict__ t2,
                                                 const int* __restrict__ sp,
                                                 int deg, int lane) {
    const int sub = lane & 7;
    const int rowi = lane >> 3;
    float4 acc = make_float4(0.f, 0.f, 0.f, 0.f);
    for (int base = 0; base < deg; base += 64) {
        int chunk = min(deg - base, 64);
        int myidx = (lane < chunk) ? sp[base + lane] : -1;
        int nit = (chunk + 7) >> 3;
        int e[8];
        float2 v[8];
#pragma unroll
        for (int it = 0; it < 8; ++it)
            e[it] = (it < nit) ? __shfl(myidx, it * 8 + rowi) : -1;
#pragma unroll
        for (int it = 0; it < 8; ++it)
            v[it] = (e[it] >= 0) ? t2[(size_t)e[it] * 8 + sub]
                                 : make_float2(0.f, 0.f);
#pragma unroll
        for (int it = 0; it < 8; ++it) {
            const __half2* hp = (const __half2*)&v[it];
            float2 lo = __half22float2(hp[0]);
            float2 hi = __half22float2(hp[1]);
            acc.x += lo.x; acc.y += lo.y; acc.z += hi.x; acc.w += hi.y;
        }
    }
#pragma unroll
    for (int off = 8; off < 64; off <<= 1) {
        acc.x += __shfl_xor(acc.x, off);
        acc.y += __shfl_xor(acc.y, off);
        acc.z += __shfl_xor(acc.z, off);
        acc.w += __shfl_xor(acc.w, off);
    }
    return acc;
}

// ---- gather1: aggMh[n] = fp16(mean-gather xh[src]) ; one wave per node ----
__global__ __launch_bounds__(256) void gather1_kernel(
        const __half* __restrict__ xh, const int* __restrict__ row_start,
        const int* __restrict__ sorted_src, __half* __restrict__ aggMh, int N) {
    const int w = threadIdx.x >> 6;
    const int lane = threadIdx.x & 63;
    const int n = blockIdx.x * 4 + w;
    if (n >= N) return;

    int rs = row_start[n];
    int re = row_start[n + 1];
    int deg = re - rs;
    float inv = 1.0f / fmaxf((float)deg, 1.0f);

    float4 acc = gather_sum_f16((const float2*)xh, sorted_src + rs, deg, lane);

    if (lane < 8) {
        __half2 h0 = __floats2half2_rn(acc.x * inv, acc.y * inv);
        __half2 h1 = __floats2half2_rn(acc.z * inv, acc.w * inv);
        unsigned u0, u1;
        __builtin_memcpy(&u0, &h0, 4);
        __builtin_memcpy(&u1, &h1, 4);
        ((uint2*)(aggMh + (size_t)n * 32))[lane] = make_uint2(u0, u1);
    }
}

// ---- dense (fused, register-weight, fdot2): 8 waves x 4 nodes / block ----
// h = relu(agg@W1l + b1 + x@W1r); hWh = fp16(h@W2l); d2 = h@W2r + b2
__global__ __launch_bounds__(512) void dense_kernel(
        const __half* __restrict__ xh, const __half* __restrict__ aggMh,
        const __half* __restrict__ wT,
        const float* __restrict__ b1, const float* __restrict__ b2,
        __half* __restrict__ hWh, float* __restrict__ d2, int N) {
    __shared__ __align__(16) __half sH[8][64];

    const int w = threadIdx.x >> 6;
    const int lane = threadIdx.x & 63;
    const int oc = lane;            // dense1 output channel
    const int c2 = lane & 31;       // dense2 output channel
    const int khalf = lane >> 5;    // dense2 k-half

    // per-lane weight rows -> registers (loaded once, amortized over 4 nodes)
    const unsigned* wT32 = (const unsigned*)wT;
    unsigned w1l[16], w1r[16], w2l[16], w2r[16];
    {
        const uint4* p1l = (const uint4*)(wT32 + oc * 16);
        const uint4* p1r = (const uint4*)(wT32 + 1024 + oc * 16);
        const uint4* p2l = (const uint4*)(wT32 + 2048 + c2 * 32 + khalf * 16);
        const uint4* p2r = (const uint4*)(wT32 + 3072 + c2 * 32 + khalf * 16);
#pragma unroll
        for (int i = 0; i < 4; ++i) {
            ((uint4*)w1l)[i] = p1l[i];
            ((uint4*)w1r)[i] = p1r[i];
            ((uint4*)w2l)[i] = p2l[i];
            ((uint4*)w2r)[i] = p2r[i];
        }
    }
    const float bias1 = b1[oc];
    const float bias2 = b2[c2];

#pragma unroll
    for (int i = 0; i < 4; ++i) {
        int n = blockIdx.x * 32 + w * 4 + i;
        if (n >= N) break;   // wave-uniform

        unsigned ag[16], xr[16];
        const uint4* pa = (const uint4*)((const unsigned*)aggMh + (size_t)n * 16);
        const uint4* px = (const uint4*)((const unsigned*)xh + (size_t)n * 16);
#pragma unroll
        for (int j = 0; j < 4; ++j) {
            ((uint4*)ag)[j] = pa[j];   // uniform-address 16B loads (broadcast)
            ((uint4*)xr)[j] = px[j];
        }

        float acc = bias1;
#pragma unroll
        for (int k = 0; k < 16; ++k) {
            acc = fdot2u(ag[k], w1l[k], acc);
            acc = fdot2u(xr[k], w1r[k], acc);
        }
        float hv = fmaxf(acc, 0.0f);
        sH[w][oc] = __float2half_rn(hv);
        // wave-internal LDS exchange (single wave owns sH[w]; compiler orders)

        unsigned hr[16];
        const uint4* ph = (const uint4*)((const unsigned*)(&sH[w][0]) + khalf * 16);
#pragma unroll
        for (int j = 0; j < 4; ++j) ((uint4*)hr)[j] = ph[j];

        float p1 = 0.f, p2v = 0.f;
#pragma unroll
        for (int k = 0; k < 16; ++k) {
            p1  = fdot2u(hr[k], w2l[k], p1);
            p2v = fdot2u(hr[k], w2r[k], p2v);
        }
        p1  += __shfl_xor(p1, 32);
        p2v += __shfl_xor(p2v, 32);
        if (lane < 32) {
            hWh[(size_t)n * 32 + c2] = __float2half_rn(p1);
            d2[(size_t)n * 32 + c2] = p2v + bias2;
        }
    }
}

// ---- layer2: out = gather-mean(hWh[src]) + d2 ----
__global__ __launch_bounds__(256) void layer2_kernel(
        const __half* __restrict__ hWh, const float* __restrict__ d2,
        const int* __restrict__ row_start, const int* __restrict__ sorted_src,
        float* __restrict__ out, int N) {
    const int w = threadIdx.x >> 6;
    const int lane = threadIdx.x & 63;
    const int n = blockIdx.x * 4 + w;
    if (n >= N) return;

    int rs = row_start[n];
    int re = row_start[n + 1];
    int deg = re - rs;
    float inv = 1.0f / fmaxf((float)deg, 1.0f);

    float4 acc = gather_sum_f16((const float2*)hWh, sorted_src + rs, deg, lane);

    if (lane < 8) {
        float4 dd = ((const float4*)d2)[(size_t)n * 8 + lane];
        float4 o;
        o.x = acc.x * inv + dd.x;
        o.y = acc.y * inv + dd.y;
        o.z = acc.z * inv + dd.z;
        o.w = acc.w * inv + dd.w;
        ((float4*)out)[(size_t)n * 8 + lane] = o;
    }
}

extern "C" void kernel_launch(void* const* d_in, const int* in_sizes, int n_in,
                              void* d_out, int out_size, void* d_ws, size_t ws_size,
                              hipStream_t stream) {
    const float* x   = (const float*)d_in[0];
    const int*   ei  = (const int*)d_in[1];
    const float* W1l = (const float*)d_in[2];
    const float* b1  = (const float*)d_in[3];
    const float* W1r = (const float*)d_in[4];
    const float* W2l = (const float*)d_in[5];
    const float* b2  = (const float*)d_in[6];
    const float* W2r = (const float*)d_in[7];
    float* out = (float*)d_out;

    const int N = in_sizes[0] / 32;    // 100000
    const int E = in_sizes[1] / 2;     // 1600000
    const int* src = ei;
    const int* dst = ei + E;
    const int NBUCK = (N + BUCKET_SPAN - 1) >> BUCKET_SHIFT;   // 391

    char* p = (char*)d_ws;
    auto align64 = [](size_t v) { return (v + 63) & ~(size_t)63; };
    int* cursorB     = (int*)p;    p += align64((size_t)NBUCK * 4);
    int* bucketStart = (int*)p;    p += align64((size_t)(NBUCK + 1) * 4);
    int* row_start   = (int*)p;    p += align64((size_t)(N + 1) * 4);
    int* sorted_src  = (int*)p;    p += align64((size_t)E * 4);
    int* edgesB      = (int*)p;    p += align64((size_t)NBUCK * BUCKET_CAP * 4);
    __half* xh       = (__half*)p; p += align64((size_t)N * 32 * 2);
    __half* aggMh    = (__half*)p; p += align64((size_t)N * 32 * 2);
    __half* hWh      = (__half*)p; p += align64((size_t)N * 32 * 2);
    float* d2        = (float*)p;  p += align64((size_t)N * 32 * 4);
    __half* wT       = (__half*)p; p += align64((size_t)8192 * 2);

    hipMemsetAsync(cursorB, 0, (size_t)NBUCK * 4, stream);

    wprep_kernel<<<1, 512, 0, stream>>>(W1l, W1r, W2l, W2r, wT);

    int total8 = N * 4;
    cast_x_kernel<<<(total8 + 255) / 256, 256, 0, stream>>>(x, xh, total8);

    int ntiles = (E + PART_TILE - 1) / PART_TILE;   // 196
    partition_kernel<<<ntiles, 256, 0, stream>>>(src, dst, cursorB, edgesB, E, NBUCK);
    bucket_scan_kernel<<<1, 512, 0, stream>>>(cursorB, bucketStart, NBUCK);
    bucket_csr_kernel<<<NBUCK, 256, 0, stream>>>(cursorB, bucketStart, edgesB,
                                                 row_start, sorted_src, N, NBUCK);

    gather1_kernel<<<(N + 3) / 4, 256, 0, stream>>>(xh, row_start, sorted_src,
                                                    aggMh, N);
    dense_kernel<<<(N + 31) / 32, 512, 0, stream>>>(xh, aggMh, wT, b1, b2,
                                                    hWh, d2, N);
    layer2_kernel<<<(N + 3) / 4, 256, 0, stream>>>(hWh, d2, row_start, sorted_src,
                                                   out, N);
}

// Round 11
// 263.395 us; speedup vs baseline: 1.0338x; 1.0338x over previous
//
#include <hip/hip_runtime.h>
#include <hip/hip_bf16.h>
#include <hip/hip_fp16.h>

// GraphSAGE 2-layer forward. N=100000, E=1.6M, C: 32 -> 64 -> 32.
//
// Round-11: round-10 failed on a grid-size slip (launched 196 blocks for a
// 64-nodes-per-block kernel -> 87k nodes left poisoned). Fix: grid=(N+63)/64.
// Everything else identical to round 10:
//  - dense: __launch_bounds__(512,2), fp16 weights register-resident,
//    8 nodes/wave ping-pong prefetch, fdot2 inner products.
//  - gather1/layer2: wave-per-node fp16 row gathers.

#define BUCKET_SHIFT 8
#define BUCKET_SPAN  256
#define BUCKET_CAP   8192
#define PART_ITEMS   32
#define PART_TILE    (256 * PART_ITEMS)   // 8192 edges
#define NPW          8                    // dense: nodes per wave

typedef _Float16 f16x2 __attribute__((ext_vector_type(2)));

__device__ __forceinline__ float fdot2u(unsigned a, unsigned b, float c) {
#if __has_builtin(__builtin_amdgcn_fdot2)
    f16x2 av, bv;
    __builtin_memcpy(&av, &a, 4);
    __builtin_memcpy(&bv, &b, 4);
    return __builtin_amdgcn_fdot2(av, bv, c, false);
#else
    __half2 ah = *reinterpret_cast<__half2*>(&a);
    __half2 bh = *reinterpret_cast<__half2*>(&b);
    float2 fa = __half22float2(ah), fb = __half22float2(bh);
    return c + fa.x * fb.x + fa.y * fb.y;
#endif
}

// ---- one-time: weights -> fp16, transposed (output-channel-major) ----
__global__ __launch_bounds__(512) void wprep_kernel(
        const float* __restrict__ W1l, const float* __restrict__ W1r,
        const float* __restrict__ W2l, const float* __restrict__ W2r,
        __half* __restrict__ wT) {
    for (int i = threadIdx.x; i < 8192; i += 512) {
        int region = i >> 11;
        int off = i & 2047;
        float v;
        if (region == 0)      { int oc = off >> 5, k = off & 31; v = W1l[k * 64 + oc]; }
        else if (region == 1) { int oc = off >> 5, k = off & 31; v = W1r[k * 64 + oc]; }
        else if (region == 2) { int c = off >> 6, k = off & 63;  v = W2l[k * 32 + c]; }
        else                  { int c = off >> 6, k = off & 63;  v = W2r[k * 32 + c]; }
        wT[i] = __float2half_rn(v);
    }
}

// ---- cast x (fp32) -> xh (fp16), 8 elems/thread ----
__global__ __launch_bounds__(256) void cast_x_kernel(
        const float* __restrict__ x, __half* __restrict__ xh, int total8) {
    int i = blockIdx.x * blockDim.x + threadIdx.x;
    if (i < total8) {
        float4 a = ((const float4*)x)[(size_t)i * 2];
        float4 b = ((const float4*)x)[(size_t)i * 2 + 1];
        struct alignas(16) H8 { __half2 a, b, c, d; } o;
        o.a = __floats2half2_rn(a.x, a.y);
        o.b = __floats2half2_rn(a.z, a.w);
        o.c = __floats2half2_rn(b.x, b.y);
        o.d = __floats2half2_rn(b.z, b.w);
        ((H8*)xh)[i] = o;
    }
}

// ---- partition: scatter edges into bucket regions, packed ----
__global__ __launch_bounds__(256) void partition_kernel(
        const int* __restrict__ src, const int* __restrict__ dst,
        int* __restrict__ cursorB, int* __restrict__ edgesB, int E, int nbuck) {
    __shared__ int hist[512];
    __shared__ int rank_[512];
    __shared__ int base[512];
    const int tid = threadIdx.x;
    const int tbase = blockIdx.x * PART_TILE;

    for (int i = tid; i < 512; i += 256) { hist[i] = 0; rank_[i] = 0; }
    __syncthreads();

#pragma unroll
    for (int it = 0; it < PART_ITEMS; ++it) {
        int idx = tbase + it * 256 + tid;
        if (idx < E) atomicAdd(&hist[dst[idx] >> BUCKET_SHIFT], 1);
    }
    __syncthreads();

    for (int i = tid; i < nbuck; i += 256) {
        int h = hist[i];
        base[i] = h ? atomicAdd(&cursorB[i], h) : 0;
    }
    __syncthreads();

#pragma unroll
    for (int it = 0; it < PART_ITEMS; ++it) {
        int idx = tbase + it * 256 + tid;
        if (idx < E) {
            int d = dst[idx];
            int b = d >> BUCKET_SHIFT;
            int ld = d & (BUCKET_SPAN - 1);
            int r = atomicAdd(&rank_[b], 1);
            edgesB[(size_t)b * BUCKET_CAP + base[b] + r] = (ld << 24) | src[idx];
        }
    }
}

__global__ __launch_bounds__(512) void bucket_scan_kernel(
        const int* __restrict__ cursorB, int* __restrict__ bucketStart, int nbuck) {
    __shared__ int s[512];
    int t = threadIdx.x;
    int v = (t < nbuck) ? cursorB[t] : 0;
    s[t] = v;
    __syncthreads();
    for (int off = 1; off < 512; off <<= 1) {
        int a = (t >= off) ? s[t - off] : 0;
        __syncthreads();
        s[t] += a;
        __syncthreads();
    }
    if (t < nbuck) bucketStart[t] = s[t] - v;
}

__global__ __launch_bounds__(256) void bucket_csr_kernel(
        const int* __restrict__ cursorB, const int* __restrict__ bucketStart,
        const int* __restrict__ edgesB, int* __restrict__ row_start,
        int* __restrict__ sorted_src, int N, int nbuck) {
    __shared__ int cnt[BUCKET_SPAN];
    __shared__ int cur[BUCKET_SPAN];
    __shared__ int sc[BUCKET_SPAN];
    __shared__ int sorted[BUCKET_CAP];

    const int b = blockIdx.x;
    const int t = threadIdx.x;
    const int nodeBase = b << BUCKET_SHIFT;
    const int span = min(BUCKET_SPAN, N - nodeBase);
    const int size = cursorB[b];
    const int gstart = bucketStart[b];
    const int* eb = edgesB + (size_t)b * BUCKET_CAP;

    cnt[t] = 0;
    __syncthreads();
    for (int i = t; i < size; i += 256) atomicAdd(&cnt[((unsigned)eb[i]) >> 24], 1);
    __syncthreads();

    sc[t] = cnt[t];
    __syncthreads();
    for (int off = 1; off < BUCKET_SPAN; off <<= 1) {
        int a = (t >= off) ? sc[t - off] : 0;
        __syncthreads();
        sc[t] += a;
        __syncthreads();
    }
    int excl = sc[t] - cnt[t];
    if (t < span) row_start[nodeBase + t] = gstart + excl;
    if (b == nbuck - 1 && t == 0) row_start[N] = gstart + size;
    cur[t] = excl;
    __syncthreads();

    for (int i = t; i < size; i += 256) {
        int p = eb[i];
        int r = atomicAdd(&cur[((unsigned)p) >> 24], 1);
        sorted[r] = p & 0xFFFFFF;
    }
    __syncthreads();
    for (int i = t; i < size; i += 256) sorted_src[gstart + i] = sorted[i];
}

// ---- wave-cooperative gather-sum of fp16 rows (32ch = 8 float2 units) ----
__device__ __forceinline__ float4 gather_sum_f16(const float2* __restrict__ t2,
                                                 const int* __restrict__ sp,
                                                 int deg, int lane) {
    const int sub = lane & 7;
    const int rowi = lane >> 3;
    float4 acc = make_float4(0.f, 0.f, 0.f, 0.f);
    for (int base = 0; base < deg; base += 64) {
        int chunk = min(deg - base, 64);
        int myidx = (lane < chunk) ? sp[base + lane] : -1;
        int nit = (chunk + 7) >> 3;
        int e[8];
        float2 v[8];
#pragma unroll
        for (int it = 0; it < 8; ++it)
            e[it] = (it < nit) ? __shfl(myidx, it * 8 + rowi) : -1;
#pragma unroll
        for (int it = 0; it < 8; ++it)
            v[it] = (e[it] >= 0) ? t2[(size_t)e[it] * 8 + sub]
                                 : make_float2(0.f, 0.f);
#pragma unroll
        for (int it = 0; it < 8; ++it) {
            const __half2* hp = (const __half2*)&v[it];
            float2 lo = __half22float2(hp[0]);
            float2 hi = __half22float2(hp[1]);
            acc.x += lo.x; acc.y += lo.y; acc.z += hi.x; acc.w += hi.y;
        }
    }
#pragma unroll
    for (int off = 8; off < 64; off <<= 1) {
        acc.x += __shfl_xor(acc.x, off);
        acc.y += __shfl_xor(acc.y, off);
        acc.z += __shfl_xor(acc.z, off);
        acc.w += __shfl_xor(acc.w, off);
    }
    return acc;
}

// ---- gather1: aggMh[n] = fp16(mean-gather xh[src]) ; one wave per node ----
__global__ __launch_bounds__(256) void gather1_kernel(
        const __half* __restrict__ xh, const int* __restrict__ row_start,
        const int* __restrict__ sorted_src, __half* __restrict__ aggMh, int N) {
    const int w = threadIdx.x >> 6;
    const int lane = threadIdx.x & 63;
    const int n = blockIdx.x * 4 + w;
    if (n >= N) return;

    int rs = row_start[n];
    int re = row_start[n + 1];
    int deg = re - rs;
    float inv = 1.0f / fmaxf((float)deg, 1.0f);

    float4 acc = gather_sum_f16((const float2*)xh, sorted_src + rs, deg, lane);

    if (lane < 8) {
        __half2 h0 = __floats2half2_rn(acc.x * inv, acc.y * inv);
        __half2 h1 = __floats2half2_rn(acc.z * inv, acc.w * inv);
        unsigned u0, u1;
        __builtin_memcpy(&u0, &h0, 4);
        __builtin_memcpy(&u1, &h1, 4);
        ((uint2*)(aggMh + (size_t)n * 32))[lane] = make_uint2(u0, u1);
    }
}

// ---- dense: register weights, fdot2, 8 nodes/wave ping-pong pipeline ----
// h = relu(agg@W1l + b1 + x@W1r); hWh = fp16(h@W2l); d2 = h@W2r + b2
// Block covers 8 waves * NPW = 64 nodes. Grid must be (N+63)/64.
__global__ __launch_bounds__(512, 2) void dense_kernel(
        const __half* __restrict__ xh, const __half* __restrict__ aggMh,
        const __half* __restrict__ wT,
        const float* __restrict__ b1, const float* __restrict__ b2,
        __half* __restrict__ hWh, float* __restrict__ d2, int N) {
    __shared__ __align__(16) __half sH[8][64];

    const int w = threadIdx.x >> 6;
    const int lane = threadIdx.x & 63;
    const int oc = lane;            // dense1 output channel
    const int c2 = lane & 31;       // dense2 output channel
    const int khalf = lane >> 5;    // dense2 k-half

    // per-lane weight rows -> registers (resident: launch_bounds(512,2))
    const unsigned* wT32 = (const unsigned*)wT;
    unsigned w1l[16], w1r[16], w2l[16], w2r[16];
    {
        const uint4* p1l = (const uint4*)(wT32 + oc * 16);
        const uint4* p1r = (const uint4*)(wT32 + 1024 + oc * 16);
        const uint4* p2l = (const uint4*)(wT32 + 2048 + c2 * 32 + khalf * 16);
        const uint4* p2r = (const uint4*)(wT32 + 3072 + c2 * 32 + khalf * 16);
#pragma unroll
        for (int i = 0; i < 4; ++i) {
            ((uint4*)w1l)[i] = p1l[i];
            ((uint4*)w1r)[i] = p1r[i];
            ((uint4*)w2l)[i] = p2l[i];
            ((uint4*)w2r)[i] = p2r[i];
        }
    }
    const float bias1 = b1[oc];
    const float bias2 = b2[c2];

    const int n0 = (blockIdx.x * 8 + w) * NPW;
    if (n0 >= N) return;   // wave-uniform; no barriers in this kernel

    uint4 agA[4], xrA[4], agB[4], xrB[4];

    auto loadNode = [&](uint4* agv, uint4* xrv, int n) {
        const uint4* pa = (const uint4*)((const unsigned*)aggMh + (size_t)n * 16);
        const uint4* px = (const uint4*)((const unsigned*)xh + (size_t)n * 16);
#pragma unroll
        for (int j = 0; j < 4; ++j) { agv[j] = pa[j]; xrv[j] = px[j]; }
    };

    auto computeNode = [&](const uint4* agv, const uint4* xrv, int n) {
        const unsigned* ag = (const unsigned*)agv;
        const unsigned* xr = (const unsigned*)xrv;
        float acc = bias1;
#pragma unroll
        for (int k = 0; k < 16; ++k) {
            acc = fdot2u(ag[k], w1l[k], acc);
            acc = fdot2u(xr[k], w1r[k], acc);
        }
        sH[w][oc] = __float2half_rn(fmaxf(acc, 0.0f));
        // wave-internal LDS exchange (in-order wave; compiler inserts lgkmcnt)
        unsigned hr[16];
        const uint4* ph = (const uint4*)((const unsigned*)(&sH[w][0]) + khalf * 16);
#pragma unroll
        for (int j = 0; j < 4; ++j) ((uint4*)hr)[j] = ph[j];
        float p1 = 0.f, p2v = 0.f;
#pragma unroll
        for (int k = 0; k < 16; ++k) {
            p1  = fdot2u(hr[k], w2l[k], p1);
            p2v = fdot2u(hr[k], w2r[k], p2v);
        }
        p1  += __shfl_xor(p1, 32);
        p2v += __shfl_xor(p2v, 32);
        if (lane < 32) {
            hWh[(size_t)n * 32 + c2] = __float2half_rn(p1);
            d2[(size_t)n * 32 + c2] = p2v + bias2;
        }
    };

    loadNode(agA, xrA, n0);
#pragma unroll
    for (int ii = 0; ii < NPW; ii += 2) {     // statically unrolled ping-pong
        int nA = n0 + ii;
        if (nA >= N) break;
        int nB = nA + 1;
        bool hasB = (ii + 1 < NPW) && (nB < N);
        if (hasB) loadNode(agB, xrB, nB);     // prefetch under compute(A)
        computeNode(agA, xrA, nA);
        int nC = n0 + ii + 2;
        bool hasC = (ii + 2 < NPW) && (nC < N);
        if (hasC) loadNode(agA, xrA, nC);     // prefetch under compute(B)
        if (hasB) computeNode(agB, xrB, nB);
    }
}

// ---- layer2: out = gather-mean(hWh[src]) + d2 ----
__global__ __launch_bounds__(256) void layer2_kernel(
        const __half* __restrict__ hWh, const float* __restrict__ d2,
        const int* __restrict__ row_start, const int* __restrict__ sorted_src,
        float* __restrict__ out, int N) {
    const int w = threadIdx.x >> 6;
    const int lane = threadIdx.x & 63;
    const int n = blockIdx.x * 4 + w;
    if (n >= N) return;

    int rs = row_start[n];
    int re = row_start[n + 1];
    int deg = re - rs;
    float inv = 1.0f / fmaxf((float)deg, 1.0f);

    float4 acc = gather_sum_f16((const float2*)hWh, sorted_src + rs, deg, lane);

    if (lane < 8) {
        float4 dd = ((const float4*)d2)[(size_t)n * 8 + lane];
        float4 o;
        o.x = acc.x * inv + dd.x;
        o.y = acc.y * inv + dd.y;
        o.z = acc.z * inv + dd.z;
        o.w = acc.w * inv + dd.w;
        ((float4*)out)[(size_t)n * 8 + lane] = o;
    }
}

extern "C" void kernel_launch(void* const* d_in, const int* in_sizes, int n_in,
                              void* d_out, int out_size, void* d_ws, size_t ws_size,
                              hipStream_t stream) {
    const float* x   = (const float*)d_in[0];
    const int*   ei  = (const int*)d_in[1];
    const float* W1l = (const float*)d_in[2];
    const float* b1  = (const float*)d_in[3];
    const float* W1r = (const float*)d_in[4];
    const float* W2l = (const float*)d_in[5];
    const float* b2  = (const float*)d_in[6];
    const float* W2r = (const float*)d_in[7];
    float* out = (float*)d_out;

    const int N = in_sizes[0] / 32;    // 100000
    const int E = in_sizes[1] / 2;     // 1600000
    const int* src = ei;
    const int* dst = ei + E;
    const int NBUCK = (N + BUCKET_SPAN - 1) >> BUCKET_SHIFT;   // 391

    char* p = (char*)d_ws;
    auto align64 = [](size_t v) { return (v + 63) & ~(size_t)63; };
    int* cursorB     = (int*)p;    p += align64((size_t)NBUCK * 4);
    int* bucketStart = (int*)p;    p += align64((size_t)(NBUCK + 1) * 4);
    int* row_start   = (int*)p;    p += align64((size_t)(N + 1) * 4);
    int* sorted_src  = (int*)p;    p += align64((size_t)E * 4);
    int* edgesB      = (int*)p;    p += align64((size_t)NBUCK * BUCKET_CAP * 4);
    __half* xh       = (__half*)p; p += align64((size_t)N * 32 * 2);
    __half* aggMh    = (__half*)p; p += align64((size_t)N * 32 * 2);
    __half* hWh      = (__half*)p; p += align64((size_t)N * 32 * 2);
    float* d2        = (float*)p;  p += align64((size_t)N * 32 * 4);
    __half* wT       = (__half*)p; p += align64((size_t)8192 * 2);

    hipMemsetAsync(cursorB, 0, (size_t)NBUCK * 4, stream);

    wprep_kernel<<<1, 512, 0, stream>>>(W1l, W1r, W2l, W2r, wT);

    int total8 = N * 4;
    cast_x_kernel<<<(total8 + 255) / 256, 256, 0, stream>>>(x, xh, total8);

    int ntiles = (E + PART_TILE - 1) / PART_TILE;   // 196
    partition_kernel<<<ntiles, 256, 0, stream>>>(src, dst, cursorB, edgesB, E, NBUCK);
    bucket_scan_kernel<<<1, 512, 0, stream>>>(cursorB, bucketStart, NBUCK);
    bucket_csr_kernel<<<NBUCK, 256, 0, stream>>>(cursorB, bucketStart, edgesB,
                                                 row_start, sorted_src, N, NBUCK);

    gather1_kernel<<<(N + 3) / 4, 256, 0, stream>>>(xh, row_start, sorted_src,
                                                    aggMh, N);
    // 64 nodes per block (8 waves x NPW)
    dense_kernel<<<(N + 63) / 64, 512, 0, stream>>>(xh, aggMh, wT, b1, b2,
                                                    hWh, d2, N);
    layer2_kernel<<<(N + 3) / 4, 256, 0, stream>>>(hWh, d2, row_start, sorted_src,
                                                   out, N);
}